// Round 4
// baseline (273.571 us; speedup 1.0000x reference)
//
#include <hip/hip_runtime.h>
#include <math.h>

// MoE Router V5: x(16384,2048) fp32, W(128,2048) fp32, bias(128) fp32
// out = [weights(16384,8) fp32 | indices(16384,8) as fp32]
//
// R7: fused router, W-in-registers structure (bit-exact with passing R6).
//  R6 post-mortem: 134.9us, MfmaUtil 15%, VALUBusy 18%, occupancy 22% ->
//  latency-bound. LDS traffic was the floor (~132 KB/chunk/CU: every wave
//  re-read 12 KB of A+B fragments) and __syncthreads drained vmcnt(0) every
//  chunk, exposing load latency 64 times.
//  Changes (none affect arithmetic: same fragment values, same 6-MFMA order
//  per accumulator, same chunk/slice order, same combine, same topk):
//   1. W bf16 planes load global->VGPR per wave (wp is L2-resident, 1.5 MB),
//      double-buffered one chunk ahead. No wsm: LDS reads/chunk halve.
//   2. Raw s_barrier + s_waitcnt lgkmcnt(0) only (x-staging is the only LDS
//      hazard); global loads stay in flight across barriers.
//   3. xsm row stride 40 shorts (80 B) spreads af-read banks; logits L
//      aliases the staging arena after the K-loop. LDS 104.5 -> 33.3 KB.

#define NE      128
#define TOKT    64
#define KC      32
#define DMODEL  2048
#define NT      (DMODEL / KC)        // 64 k-chunks
#define CHUNK_SH (3 * NE * KC)       // 12288 shorts per chunk image
#define XPAD    40                   // xsm row stride in shorts (80 B)

typedef __attribute__((ext_vector_type(8))) short short8;
typedef __attribute__((ext_vector_type(4))) short s16x4;
typedef __attribute__((ext_vector_type(4))) float f32x4;

union S4u { short s[4]; s16x4 v; };

// split one fp32 into 3 truncated bf16 planes (exact residuals)
__device__ __forceinline__ void split3(float f, S4u& hi, S4u& mi, S4u& lo, int j) {
  const unsigned u0 = __float_as_uint(f);
  const float hif = __uint_as_float(u0 & 0xFFFF0000u);
  const float r1 = f - hif;                      // exact
  const unsigned u1 = __float_as_uint(r1);
  const float mif = __uint_as_float(u1 & 0xFFFF0000u);
  const float r2 = r1 - mif;                     // exact
  hi.s[j] = (short)(u0 >> 16);
  mi.s[j] = (short)(u1 >> 16);
  lo.s[j] = (short)(__float_as_uint(r2) >> 16);
}

// W planes precompute: wp[chunk][p][e][kk], identical split3 as x path.
__global__ __launch_bounds__(256) void wprep(const float* __restrict__ w,
                                             short* __restrict__ wp) {
  const int gid = blockIdx.x * 256 + threadIdx.x;  // 65536 threads
  const int e = gid >> 9;                          // expert 0..127
  const int g = gid & 511;                         // float4 group in row
  const int k = g << 2;
  const int chunk = k >> 5;
  const int kk = k & 31;
  const f32x4 a = *(const f32x4*)(w + (size_t)e * DMODEL + k);
  S4u hi, mi, lo;
  split3(a[0], hi, mi, lo, 0); split3(a[1], hi, mi, lo, 1);
  split3(a[2], hi, mi, lo, 2); split3(a[3], hi, mi, lo, 3);
  short* base = wp + (size_t)chunk * CHUNK_SH + (size_t)e * KC + kk;
  *(s16x4*)(base)               = hi.v;
  *(s16x4*)(base + NE * KC)     = mi.v;
  *(s16x4*)(base + 2 * NE * KC) = lo.v;
}

__global__ __launch_bounds__(512) void router_fused(
    const float* __restrict__ x, const short* __restrict__ wp,
    const float* __restrict__ bias, float* __restrict__ outW,
    float* __restrict__ outI, int N) {
  // arena: xsm[2][3][64][XPAD] shorts (30720 B) during K-loop,
  //        L[64][130] floats (33280 B) afterwards.
  __shared__ __align__(16) char arena[TOKT * (NE + 2) * 4];
  typedef short XsmT[3][TOKT][XPAD];
  XsmT* xsm = (XsmT*)arena;                       // xsm[buf][p][row][k]
  float (*L)[NE + 2] = (float (*)[NE + 2])arena;  // stride 130 floats

  const int tid  = threadIdx.x;
  const int wv   = tid >> 6;        // 0..7
  const int lane = tid & 63;
  const int wm   = wv >> 2;         // token half (0..1)
  const int wn   = wv & 3;          // expert quarter (0..3)
  const int quad = lane >> 4;
  const int l16  = lane & 15;
  const size_t tokBase = (size_t)blockIdx.x * TOKT;

  // x staging: thread -> (row r, 4-float group kq) of the 64x32 chunk
  const int r  = tid >> 3;          // 0..63
  const int kq = tid & 7;           // 0..7
  const float* xg = x + (tokBase + r) * (size_t)DMODEL + kq * 4;

  // per-lane W fragment base: expert row (wn*32 + nt*16 + l16), cols quad*8..
  const short* wfb = wp + (size_t)(wn * 32 + l16) * KC + quad * 8;

  // 4 slice accumulators (R3/R6 split-K order); ALL indexing compile-time.
  f32x4 accs[4][2][2];
#pragma unroll
  for (int s = 0; s < 4; ++s)
#pragma unroll
    for (int i = 0; i < 2; ++i)
#pragma unroll
      for (int j = 0; j < 2; ++j) accs[s][i][j] = (f32x4)(0.f);

  // ---- helpers (buf literal at call sites -> constant-folds) ----
  auto load_bf = [&](short8 (&bf)[2][3], int c) {
    const short* b = wfb + (size_t)c * CHUNK_SH;
#pragma unroll
    for (int nt = 0; nt < 2; ++nt)
#pragma unroll
      for (int p = 0; p < 3; ++p)
        bf[nt][p] = *(const short8*)(b + p * (NE * KC) + nt * 16 * KC);
  };
  auto stage_x = [&](int buf, f32x4 xr) {
    S4u hi, mi, lo;
    split3(xr[0], hi, mi, lo, 0); split3(xr[1], hi, mi, lo, 1);
    split3(xr[2], hi, mi, lo, 2); split3(xr[3], hi, mi, lo, 3);
    *(s16x4*)&xsm[buf][0][r][kq * 4] = hi.v;
    *(s16x4*)&xsm[buf][1][r][kq * 4] = mi.v;
    *(s16x4*)&xsm[buf][2][r][kq * 4] = lo.v;
  };
  auto compute = [&](int buf, const short8 (&bf)[2][3], f32x4 (&acc)[2][2]) {
    short8 af[2][3];
#pragma unroll
    for (int mt = 0; mt < 2; ++mt)
#pragma unroll
      for (int p = 0; p < 3; ++p)
        af[mt][p] = *(const short8*)&xsm[buf][p][wm * 32 + mt * 16 + l16][quad * 8];
#pragma unroll
    for (int nt = 0; nt < 2; ++nt)
#pragma unroll
      for (int mt = 0; mt < 2; ++mt) {
        f32x4 c = acc[mt][nt];
        c = __builtin_amdgcn_mfma_f32_16x16x32_bf16(af[mt][0], bf[nt][0], c, 0, 0, 0); // x1w1
        c = __builtin_amdgcn_mfma_f32_16x16x32_bf16(af[mt][0], bf[nt][1], c, 0, 0, 0); // x1w2
        c = __builtin_amdgcn_mfma_f32_16x16x32_bf16(af[mt][1], bf[nt][0], c, 0, 0, 0); // x2w1
        c = __builtin_amdgcn_mfma_f32_16x16x32_bf16(af[mt][0], bf[nt][2], c, 0, 0, 0); // x1w3
        c = __builtin_amdgcn_mfma_f32_16x16x32_bf16(af[mt][2], bf[nt][0], c, 0, 0, 0); // x3w1
        c = __builtin_amdgcn_mfma_f32_16x16x32_bf16(af[mt][1], bf[nt][1], c, 0, 0, 0); // x2w2
        acc[mt][nt] = c;
      }
  };
  auto lds_barrier = [&]() {
    asm volatile("s_waitcnt lgkmcnt(0)" ::: "memory");
    __builtin_amdgcn_s_barrier();
  };

  // ---- prologue: bfA = W chunk 0; x chunks 0,1 in regs; xsm buf0 = chunk 0
  short8 bfA[2][3], bfB[2][3];
  load_bf(bfA, 0);
  f32x4 xra = *(const f32x4*)(xg);        // x chunk 0
  f32x4 xrb = *(const f32x4*)(xg + KC);   // x chunk 1
  stage_x(0, xra);
  lds_barrier();

  // ---- main K loop: slice loop unrolled (static accs[s]), chunk loop rolled.
#pragma unroll
  for (int s = 0; s < 4; ++s) {
#pragma unroll 1
    for (int u = 0; u < 16; u += 2) {
      const int t = s * 16 + u;
      // even body: compute chunk t (buf0, bfA); prefetch W t+1, x t+2
      if (t + 1 < NT) load_bf(bfB, t + 1);
      if (t + 2 < NT) xra = *(const f32x4*)(xg + (t + 2) * KC);
      compute(0, bfA, accs[s]);
      if (t + 1 < NT) { stage_x(1, xrb); lds_barrier(); }
      // odd body: compute chunk t+1 (buf1, bfB); prefetch W t+2, x t+3
      if (t + 2 < NT) load_bf(bfA, t + 2);
      if (t + 3 < NT) xrb = *(const f32x4*)(xg + (t + 3) * KC);
      if (t + 1 < NT) compute(1, bfB, accs[s]);
      if (t + 2 < NT) { stage_x(0, xra); lds_barrier(); }
    }
  }

  // arena reuse: make sure every wave is done with xsm before L overwrites it
  __syncthreads();

  // ---- combine slices in R3/R6 order (((p0+p1)+p2)+p3) -> logits LDS.
  // C/D layout: col(expert)=l16, row(token)=quad*4+reg  (verified)
#pragma unroll
  for (int mt = 0; mt < 2; ++mt)
#pragma unroll
    for (int nt = 0; nt < 2; ++nt)
#pragma unroll
      for (int reg = 0; reg < 4; ++reg) {
        float v = accs[0][mt][nt][reg];
        v += accs[1][mt][nt][reg];
        v += accs[2][mt][nt][reg];
        v += accs[3][mt][nt][reg];
        L[wm * 32 + mt * 16 + quad * 4 + reg][wn * 32 + nt * 16 + l16] = v;
      }
  __syncthreads();

  // ---- softmax + top-8 + L2 normalize (verified wave-per-token code)
  const float bmy0 = bias[lane];
  const float bmy1 = bias[lane + 64];
  for (int i = 0; i < 8; ++i) {
    const int tk = wv * 8 + i;
    const float l0 = L[tk][lane];
    const float l1 = L[tk][lane + 64];

    float m = fmaxf(l0, l1);
#pragma unroll
    for (int off = 1; off < 64; off <<= 1) m = fmaxf(m, __shfl_xor(m, off));
    const float ev0 = __expf(l0 - m);
    const float ev1 = __expf(l1 - m);
    float zs = ev0 + ev1;
#pragma unroll
    for (int off = 1; off < 64; off <<= 1) zs += __shfl_xor(zs, off);
    const float s0 = ev0 / zs;
    const float s1 = ev1 / zs;

    float b0 = s0 + bmy0;
    float b1 = s1 + bmy1;

    float myv = 0.f;
    int myi = 0;
    float ss = 0.f;
#pragma unroll
    for (int rnd = 0; rnd < 8; ++rnd) {
      float key; int idx;
      if (b0 >= b1) { key = b0; idx = lane; }
      else          { key = b1; idx = lane + 64; }
#pragma unroll
      for (int off = 1; off < 64; off <<= 1) {
        const float k2 = __shfl_xor(key, off);
        const int   i2 = __shfl_xor(idx, off);
        if (k2 > key || (k2 == key && i2 < idx)) { key = k2; idx = i2; }
      }
      const float cand = (idx < 64) ? s0 : s1;
      const float sw = __shfl(cand, idx & 63);
      ss = fmaf(sw, sw, ss);
      if (lane == rnd) { myv = sw; myi = idx; }
      if (lane == (idx & 63)) { if (idx < 64) b0 = -INFINITY; else b1 = -INFINITY; }
    }

    const float inv = 1.f / sqrtf(ss);
    if (lane < 8) {
      const size_t tok = tokBase + tk;
      outW[tok * 8 + lane] = myv * inv;
      outI[tok * 8 + lane] = (float)myi;
    }
  }
}

extern "C" void kernel_launch(void* const* d_in, const int* in_sizes, int n_in,
                              void* d_out, int out_size, void* d_ws, size_t ws_size,
                              hipStream_t stream) {
  const float* x    = (const float*)d_in[0];
  const float* w    = (const float*)d_in[1];
  const float* bias = (const float*)d_in[2];
  float* out = (float*)d_out;

  const int N = in_sizes[0] / DMODEL;  // 16384 tokens
  short* wp = (short*)d_ws;            // 64 chunks * 12288 shorts * 2 B = 1.5 MiB

  wprep<<<256, 256, 0, stream>>>(w, wp);
  router_fused<<<N / TOKT, 512, 0, stream>>>(x, wp, bias, out, out + (size_t)N * 8, N);
}